// Round 11
// baseline (357.489 us; speedup 1.0000x reference)
//
#include <hip/hip_runtime.h>

#define IN_F 1024
#define ASS 100000
#define OUT_F 1024
#define TOTAL (IN_F + ASS + OUT_F)  // 102048
#define ASS0 IN_F
#define OUT0 (IN_F + ASS)
#define NDST (ASS + OUT_F)  // 101024 destinations, node = ASS0 + d
#define NUM_ROUNDS 24

#define BIN_SZ 256  // dst nodes per bin (8 bits of payload)
#define NBINS ((NDST + BIN_SZ - 1) / BIN_SZ)  // 395
#define NCON 512    // construction blocks (2 blocks/CU with 1024 thr)
#define CON_T 1024  // construction threads per block
#define KR_T 1024   // kR threads per block (16 waves per bin)

typedef int i4v __attribute__((ext_vector_type(4)));
typedef float f4v __attribute__((ext_vector_type(4)));
typedef unsigned int u2v __attribute__((ext_vector_type(2)));

// ---------------------------------------------------------------------------
// Each assoc neuron fires exactly once at BFS level L(u).
// csr[e] = {src<<8 | dstoff, w} packed 8B; NT scattered store (no L2
// write-allocate). ltv[node] = {lev, tanh snapshot} packed 8B: one gather
// per edge. Round r: one 1024-thread block owns each 256-dst bin; edge loop
// unrolled 4x for gather MLP. Empty rounds no-op via flags[r].
// Torn-8B-read safety: ltv writes only transition lev 255->r+1, so a reader
// checking lev==r can never pair a stale tv with a matching lev.
// ---------------------------------------------------------------------------

__global__ __launch_bounds__(256) void kz(float* mem, u2v* ltv, int* flags,
                                          int* bin_count) {
  int i = blockIdx.x * 256 + threadIdx.x;
  int gs = gridDim.x * 256;
  u2v init;
  init.x = 255u;
  init.y = 0u;
  for (int k = i; k < TOTAL; k += gs) {
    mem[k] = 0.f;
    ltv[k] = init;
  }
  for (int k = i; k < NBINS; k += gs) bin_count[k] = 0;
  if (i < 32) flags[i] = 0;
}

__global__ __launch_bounds__(256) void ki(const float* __restrict__ x,
                                          const float* __restrict__ iw,
                                          const int* __restrict__ ies,
                                          const int* __restrict__ ied, int E_in,
                                          float* mem, unsigned int* ltv_raw) {
  int e = blockIdx.x * 256 + threadIdx.x;
  if (e < E_in) {
    int d = ied[e];
    atomicAdd(&mem[d], x[ies[e]] * iw[e]);
    ltv_raw[2 * d] = 0u;  // lev = 0; benign race, all writers store 0
  }
}

// snapshot level-0 frontier: tv = tanh(mem), mem = 0
__global__ __launch_bounds__(256) void kp(float* mem, u2v* ltv) {
  int i = blockIdx.x * 256 + threadIdx.x;
  if (i < ASS) {
    int node = ASS0 + i;
    u2v lt = ltv[node];
    if (lt.x == 0u) {
      lt.y = __float_as_uint(tanhf(mem[node]));
      ltv[node] = lt;
      mem[node] = 0.f;
    }
  }
}

// per-block histogram -> h_all[bin*NCON + block]; totals -> bin_count
// cacheable loads: aed stays hot in L3 for kc's re-read
__global__ __launch_bounds__(CON_T) void kh(const int* __restrict__ aed,
                                            int E_a, int* h_all,
                                            int* bin_count) {
  __shared__ int h[NBINS];
  for (int b = threadIdx.x; b < NBINS; b += CON_T) h[b] = 0;
  __syncthreads();
  const i4v* aed4 = (const i4v*)aed;
  int nv4 = E_a >> 2;
  int stride = gridDim.x * CON_T;
  for (int v = blockIdx.x * CON_T + (int)threadIdx.x; v < nv4; v += stride) {
    i4v d4 = aed4[v];
    atomicAdd(&h[(d4.x - ASS0) >> 8], 1);
    atomicAdd(&h[(d4.y - ASS0) >> 8], 1);
    atomicAdd(&h[(d4.z - ASS0) >> 8], 1);
    atomicAdd(&h[(d4.w - ASS0) >> 8], 1);
  }
  if (blockIdx.x == 0) {
    for (int e = (nv4 << 2) + (int)threadIdx.x; e < E_a; e += CON_T)
      atomicAdd(&h[(aed[e] - ASS0) >> 8], 1);
  }
  __syncthreads();
  for (int b = threadIdx.x; b < NBINS; b += CON_T) {
    int c = h[b];
    h_all[b * NCON + blockIdx.x] = c;
    if (c) atomicAdd(&bin_count[b], c);
  }
}

// exclusive scan of bin counts (single block)
__global__ __launch_bounds__(256) void ks(const int* __restrict__ bin_count,
                                          int* bin_start) {
  __shared__ int sb[1024];
  __shared__ int sp[256];
  int tid = threadIdx.x;
  for (int k = 0; k < 4; ++k) {
    int t = tid + k * 256;
    sb[t] = (t < NBINS) ? bin_count[t] : 0;
  }
  __syncthreads();
  int i0 = tid * 4;
  int s = sb[i0] + sb[i0 + 1] + sb[i0 + 2] + sb[i0 + 3];
  sp[tid] = s;
  __syncthreads();
  for (int off = 1; off < 256; off <<= 1) {
    int v = (tid >= off) ? sp[tid - off] : 0;
    __syncthreads();
    sp[tid] += v;
    __syncthreads();
  }
  int run = (tid > 0) ? sp[tid - 1] : 0;
  for (int j = 0; j < 4; ++j) {
    int t = i0 + j;
    if (t < NBINS) bin_start[t] = run;
    run += sb[t];
  }
  if (tid == 255) bin_start[NBINS] = sp[255];
}

// per-bin column scan over NCON=512 block columns
__global__ __launch_bounds__(512) void ks2(const int* __restrict__ bin_start,
                                           int* h_all) {
  __shared__ int sp[512];
  int b = blockIdx.x;
  int tid = threadIdx.x;
  int v = h_all[b * NCON + tid];
  sp[tid] = v;
  __syncthreads();
  for (int off = 1; off < 512; off <<= 1) {
    int t = (tid >= off) ? sp[tid - off] : 0;
    __syncthreads();
    sp[tid] += t;
    __syncthreads();
  }
  h_all[b * NCON + tid] = bin_start[b] + sp[tid] - v;  // exclusive
}

// single-pass scatter with exact precomputed per-(block,bin) bases;
// ONE 8B nontemporal store per edge (no L2 write-allocate)
__global__ __launch_bounds__(CON_T) void kc(const int* __restrict__ aes,
                                            const int* __restrict__ aed,
                                            const float* __restrict__ aw,
                                            int E_a,
                                            const int* __restrict__ h_all,
                                            u2v* __restrict__ csr) {
  __shared__ int cur[NBINS];
  for (int b = threadIdx.x; b < NBINS; b += CON_T)
    cur[b] = h_all[b * NCON + blockIdx.x];
  __syncthreads();
  const i4v* aed4 = (const i4v*)aed;
  const i4v* aes4 = (const i4v*)aes;
  const f4v* aw4 = (const f4v*)aw;
  int nv4 = E_a >> 2;
  int stride = gridDim.x * CON_T;
  for (int v = blockIdx.x * CON_T + (int)threadIdx.x; v < nv4; v += stride) {
    i4v d4 = aed4[v];  // L3-hot from kh
    i4v s4 = __builtin_nontemporal_load(&aes4[v]);
    f4v w4 = __builtin_nontemporal_load(&aw4[v]);
#pragma unroll
    for (int j = 0; j < 4; ++j) {
      int d = d4[j] - ASS0;
      int pos = atomicAdd(&cur[d >> 8], 1);
      u2v q;
      q.x = ((unsigned)s4[j] << 8) | (unsigned)(d & 255);
      q.y = __float_as_uint(w4[j]);
      __builtin_nontemporal_store(q, &csr[pos]);
    }
  }
  if (blockIdx.x == 0) {
    for (int e = (nv4 << 2) + (int)threadIdx.x; e < E_a; e += CON_T) {
      int d = aed[e] - ASS0;
      int pos = atomicAdd(&cur[d >> 8], 1);
      u2v q;
      q.x = ((unsigned)aes[e] << 8) | (unsigned)(d & 255);
      q.y = __float_as_uint(aw[e]);
      __builtin_nontemporal_store(q, &csr[pos]);
    }
  }
}

// one propagation round; grid = NBINS blocks x 1024 threads; 4x unrolled
__global__ __launch_bounds__(KR_T) void kR(int r, int* flags,
                                           const int* __restrict__ bin_start,
                                           const u2v* __restrict__ csr,
                                           float* __restrict__ mem,
                                           u2v* __restrict__ ltv) {
  if (r > 0 && flags[r] == 0) return;  // uniform: empty round is a no-op
  __shared__ float slice[BIN_SZ];
  __shared__ int smask[BIN_SZ];
  __shared__ int newfront;
  int tid = threadIdx.x;
  int bin = blockIdx.x;
  if (tid < BIN_SZ) {
    slice[tid] = 0.f;
    smask[tid] = 0;
  }
  if (tid == 0) newfront = 0;
  __syncthreads();
  int e0 = bin_start[bin], e1 = bin_start[bin + 1];
  unsigned rl = (unsigned)r;
  int e = e0 + tid;
  // 4x unrolled main loop: batch 4 stream loads, then 4 gathers (MLP)
  for (; e + 3 * KR_T < e1; e += 4 * KR_T) {
    u2v q0 = __builtin_nontemporal_load(&csr[e]);
    u2v q1 = __builtin_nontemporal_load(&csr[e + KR_T]);
    u2v q2 = __builtin_nontemporal_load(&csr[e + 2 * KR_T]);
    u2v q3 = __builtin_nontemporal_load(&csr[e + 3 * KR_T]);
    u2v l0 = ltv[q0.x >> 8];
    u2v l1 = ltv[q1.x >> 8];
    u2v l2 = ltv[q2.x >> 8];
    u2v l3 = ltv[q3.x >> 8];
    if (l0.x == rl) {
      atomicAdd(&slice[q0.x & 255],
                __uint_as_float(l0.y) * __uint_as_float(q0.y));
      smask[q0.x & 255] = 1;
    }
    if (l1.x == rl) {
      atomicAdd(&slice[q1.x & 255],
                __uint_as_float(l1.y) * __uint_as_float(q1.y));
      smask[q1.x & 255] = 1;
    }
    if (l2.x == rl) {
      atomicAdd(&slice[q2.x & 255],
                __uint_as_float(l2.y) * __uint_as_float(q2.y));
      smask[q2.x & 255] = 1;
    }
    if (l3.x == rl) {
      atomicAdd(&slice[q3.x & 255],
                __uint_as_float(l3.y) * __uint_as_float(q3.y));
      smask[q3.x & 255] = 1;
    }
  }
  for (; e < e1; e += KR_T) {
    u2v q = __builtin_nontemporal_load(&csr[e]);
    u2v lt = ltv[q.x >> 8];
    if (lt.x == rl) {
      atomicAdd(&slice[q.x & 255],
                __uint_as_float(lt.y) * __uint_as_float(q.y));
      smask[q.x & 255] = 1;
    }
  }
  __syncthreads();
  if (tid < BIN_SZ) {
    int d = bin * BIN_SZ + tid;
    if (d < NDST && smask[tid]) {
      int node = ASS0 + d;
      float nv = mem[node] + slice[tid];
      u2v lt = ltv[node];  // only this block ever writes this node's ltv
      if (lt.x == 255u) {  // first receipt: becomes working, fires next round
        u2v nl;
        nl.x = (unsigned)(r + 1);
        if (node < OUT0) {
          nl.y = __float_as_uint(tanhf(nv));  // snapshot at fire time
          ltv[node] = nl;
          mem[node] = 0.f;  // fired neurons erase memory
          newfront = 1;     // benign LDS race
        } else {
          nl.y = 0u;
          ltv[node] = nl;
          mem[node] = nv;  // outputs never fire, just accumulate
        }
      } else {
        mem[node] = nv;  // already fired/working: keep accumulating
      }
    }
  }
  __syncthreads();
  if (tid == 0 && newfront) flags[r + 1] = 1;
}

__global__ __launch_bounds__(256) void ko(const float* __restrict__ mem,
                                          float* __restrict__ out) {
  int i = blockIdx.x * 256 + threadIdx.x;
  if (i < OUT_F) out[i] = tanhf(mem[OUT0 + i]);
}

// ---------------------------------------------------------------------------
// Fallback dense multi-kernel path if ws too small.
// ---------------------------------------------------------------------------

__global__ __launch_bounds__(256) void k_init(float* mem, float* delta,
                                              int* status, int* got) {
  int i = blockIdx.x * 256 + threadIdx.x;
  if (i < TOTAL) {
    mem[i] = 0.f;
    delta[i] = 0.f;
    status[i] = 0;
    got[i] = 0;
  }
}
__global__ __launch_bounds__(256) void k_input(const float* __restrict__ x,
                                               const float* __restrict__ w,
                                               const int* __restrict__ src,
                                               const int* __restrict__ dst,
                                               int n, float* mem, int* got) {
  for (int e = blockIdx.x * 256 + threadIdx.x; e < n; e += gridDim.x * 256) {
    atomicAdd(&mem[dst[e]], x[src[e]] * w[e]);
    got[dst[e]] = 1;
  }
}
__global__ __launch_bounds__(256) void k_status0(int* status, int* got) {
  int i = blockIdx.x * 256 + threadIdx.x;
  if (i < TOTAL) {
    status[i] = got[i] ? 1 : 0;
    got[i] = 0;
  }
}
__global__ __launch_bounds__(256) void k_edge(const float* __restrict__ w,
                                              const int* __restrict__ src,
                                              const int* __restrict__ dst,
                                              int n,
                                              const float* __restrict__ mem,
                                              const int* __restrict__ status,
                                              float* delta, int* got) {
  for (int e = blockIdx.x * 256 + threadIdx.x; e < n; e += gridDim.x * 256) {
    int s = src[e];
    if (status[s] == 1) {
      atomicAdd(&delta[dst[e]], tanhf(mem[s]) * w[e]);
      got[dst[e]] = 1;
    }
  }
}
__global__ __launch_bounds__(256) void k_update(float* mem, float* delta,
                                                int* status, int* got) {
  int i = blockIdx.x * 256 + threadIdx.x;
  if (i < TOTAL) {
    int st = status[i];
    bool fire = (st == 1) && (i >= ASS0) && (i < OUT0);
    float d = delta[i];
    mem[i] = fire ? d : (mem[i] + d);
    status[i] = fire ? 2 : ((got[i] && st == 0) ? 1 : st);
    delta[i] = 0.f;
    got[i] = 0;
  }
}

extern "C" void kernel_launch(void* const* d_in, const int* in_sizes, int n_in,
                              void* d_out, int out_size, void* d_ws,
                              size_t ws_size, hipStream_t stream) {
  const float* x = (const float*)d_in[0];
  const float* iw = (const float*)d_in[1];
  const float* aw = (const float*)d_in[2];
  const int* ies = (const int*)d_in[3];
  const int* ied = (const int*)d_in[4];
  const int* aes = (const int*)d_in[5];
  const int* aed = (const int*)d_in[6];
  int E_in = in_sizes[1];
  int E_a = in_sizes[2];
  float* out = (float*)d_out;
  char* ws = (char*)d_ws;

  // layout (8B-aligned first): csr | ltv | mem | h_all | bin_count |
  //   bin_start | flags
  size_t off_csr = 0;
  size_t off_ltv = off_csr + (size_t)E_a * 8;
  size_t off_mem = off_ltv + (size_t)TOTAL * 8;
  size_t off_hall = off_mem + (size_t)TOTAL * 4;
  size_t off_bcnt = off_hall + (size_t)NBINS * NCON * 4;
  size_t off_bst = off_bcnt + (size_t)NBINS * 4;
  size_t off_flags = off_bst + (size_t)(NBINS + 1) * 4;
  size_t need = off_flags + 32 * 4;

  if (ws_size >= need) {
    u2v* csr = (u2v*)(ws + off_csr);
    u2v* ltv = (u2v*)(ws + off_ltv);
    float* mem = (float*)(ws + off_mem);
    int* h_all = (int*)(ws + off_hall);
    int* bin_count = (int*)(ws + off_bcnt);
    int* bin_start = (int*)(ws + off_bst);
    int* flags = (int*)(ws + off_flags);

    kz<<<(TOTAL + 255) / 256, 256, 0, stream>>>(mem, ltv, flags, bin_count);
    ki<<<(E_in + 255) / 256, 256, 0, stream>>>(x, iw, ies, ied, E_in, mem,
                                               (unsigned int*)ltv);
    kp<<<(ASS + 255) / 256, 256, 0, stream>>>(mem, ltv);
    kh<<<NCON, CON_T, 0, stream>>>(aed, E_a, h_all, bin_count);
    ks<<<1, 256, 0, stream>>>(bin_count, bin_start);
    ks2<<<NBINS, 512, 0, stream>>>(bin_start, h_all);
    kc<<<NCON, CON_T, 0, stream>>>(aes, aed, aw, E_a, h_all, csr);

    for (int r = 0; r < NUM_ROUNDS; ++r)
      kR<<<NBINS, KR_T, 0, stream>>>(r, flags, bin_start, csr, mem, ltv);

    ko<<<(OUT_F + 255) / 256, 256, 0, stream>>>(mem, out);
    return;
  }

  // fallback: dense path
  float* mem = (float*)ws;
  float* delta = mem + TOTAL;
  int* status = (int*)(delta + TOTAL);
  int* got = status + TOTAL;
  const int nodeBlocks = (TOTAL + 255) / 256;
  k_init<<<nodeBlocks, 256, 0, stream>>>(mem, delta, status, got);
  int inBlocks = (E_in + 255) / 256;
  if (inBlocks > 1024) inBlocks = 1024;
  k_input<<<inBlocks, 256, 0, stream>>>(x, iw, ies, ied, E_in, mem, got);
  k_status0<<<nodeBlocks, 256, 0, stream>>>(status, got);
  int eBlocks = (E_a + 255) / 256;
  if (eBlocks > 2048) eBlocks = 2048;
  for (int r = 0; r < NUM_ROUNDS; ++r) {
    k_edge<<<eBlocks, 256, 0, stream>>>(aw, aes, aed, E_a, mem, status, delta,
                                        got);
    k_update<<<nodeBlocks, 256, 0, stream>>>(mem, delta, status, got);
  }
  ko<<<(OUT_F + 255) / 256, 256, 0, stream>>>(mem, out);
}

// Round 12
// 194.071 us; speedup vs baseline: 1.8421x; 1.8421x over previous
//
#include <hip/hip_runtime.h>

#define IN_F 1024
#define ASS 100000
#define OUT_F 1024
#define TOTAL (IN_F + ASS + OUT_F)  // 102048
#define ASS0 IN_F
#define OUT0 (IN_F + ASS)
#define NDST (ASS + OUT_F)  // 101024 destinations, node = ASS0 + d
#define NUM_ROUNDS 24

#define BIN_SZ 256  // dst nodes per bin (8 bits of payload)
#define NBINS ((NDST + BIN_SZ - 1) / BIN_SZ)  // 395
#define NCON 512    // construction blocks (2 blocks/CU with 1024 thr)
#define CON_T 1024  // construction threads per block
#define KR_T 1024   // kR threads per block (16 waves per bin)

typedef int i4v __attribute__((ext_vector_type(4)));
typedef float f4v __attribute__((ext_vector_type(4)));
typedef unsigned int u2v __attribute__((ext_vector_type(2)));

// ---------------------------------------------------------------------------
// Each assoc neuron fires exactly once at BFS level L(u).
// csr[e] = {src<<8 | dstoff, w} packed 8B; ONE plain cached 8B scattered
// store in kc (L2 write-combines same-bin neighbors; NT store measured 2.1x
// WORSE -- partial-line HBM writes). ltv[node] = {lev, tanh snapshot} packed
// 8B: one gather per edge. Round r: one 1024-thread block owns each 256-dst
// bin; edge loop unrolled 4x for gather MLP. Empty rounds no-op via flags[r].
// Torn-8B-read safety: ltv writes only transition lev 255->r+1, so a reader
// checking lev==r can never pair a stale tv with a matching lev.
// ---------------------------------------------------------------------------

__global__ __launch_bounds__(256) void kz(float* mem, u2v* ltv, int* flags,
                                          int* bin_count) {
  int i = blockIdx.x * 256 + threadIdx.x;
  int gs = gridDim.x * 256;
  u2v init;
  init.x = 255u;
  init.y = 0u;
  for (int k = i; k < TOTAL; k += gs) {
    mem[k] = 0.f;
    ltv[k] = init;
  }
  for (int k = i; k < NBINS; k += gs) bin_count[k] = 0;
  if (i < 32) flags[i] = 0;
}

__global__ __launch_bounds__(256) void ki(const float* __restrict__ x,
                                          const float* __restrict__ iw,
                                          const int* __restrict__ ies,
                                          const int* __restrict__ ied, int E_in,
                                          float* mem, unsigned int* ltv_raw) {
  int e = blockIdx.x * 256 + threadIdx.x;
  if (e < E_in) {
    int d = ied[e];
    atomicAdd(&mem[d], x[ies[e]] * iw[e]);
    ltv_raw[2 * d] = 0u;  // lev = 0; benign race, all writers store 0
  }
}

// snapshot level-0 frontier: tv = tanh(mem), mem = 0
__global__ __launch_bounds__(256) void kp(float* mem, u2v* ltv) {
  int i = blockIdx.x * 256 + threadIdx.x;
  if (i < ASS) {
    int node = ASS0 + i;
    u2v lt = ltv[node];
    if (lt.x == 0u) {
      lt.y = __float_as_uint(tanhf(mem[node]));
      ltv[node] = lt;
      mem[node] = 0.f;
    }
  }
}

// per-block histogram -> h_all[bin*NCON + block]; totals -> bin_count
// cacheable loads: aed stays hot in L3 for kc's re-read
__global__ __launch_bounds__(CON_T) void kh(const int* __restrict__ aed,
                                            int E_a, int* h_all,
                                            int* bin_count) {
  __shared__ int h[NBINS];
  for (int b = threadIdx.x; b < NBINS; b += CON_T) h[b] = 0;
  __syncthreads();
  const i4v* aed4 = (const i4v*)aed;
  int nv4 = E_a >> 2;
  int stride = gridDim.x * CON_T;
  for (int v = blockIdx.x * CON_T + (int)threadIdx.x; v < nv4; v += stride) {
    i4v d4 = aed4[v];
    atomicAdd(&h[(d4.x - ASS0) >> 8], 1);
    atomicAdd(&h[(d4.y - ASS0) >> 8], 1);
    atomicAdd(&h[(d4.z - ASS0) >> 8], 1);
    atomicAdd(&h[(d4.w - ASS0) >> 8], 1);
  }
  if (blockIdx.x == 0) {
    for (int e = (nv4 << 2) + (int)threadIdx.x; e < E_a; e += CON_T)
      atomicAdd(&h[(aed[e] - ASS0) >> 8], 1);
  }
  __syncthreads();
  for (int b = threadIdx.x; b < NBINS; b += CON_T) {
    int c = h[b];
    h_all[b * NCON + blockIdx.x] = c;
    if (c) atomicAdd(&bin_count[b], c);
  }
}

// exclusive scan of bin counts (single block)
__global__ __launch_bounds__(256) void ks(const int* __restrict__ bin_count,
                                          int* bin_start) {
  __shared__ int sb[1024];
  __shared__ int sp[256];
  int tid = threadIdx.x;
  for (int k = 0; k < 4; ++k) {
    int t = tid + k * 256;
    sb[t] = (t < NBINS) ? bin_count[t] : 0;
  }
  __syncthreads();
  int i0 = tid * 4;
  int s = sb[i0] + sb[i0 + 1] + sb[i0 + 2] + sb[i0 + 3];
  sp[tid] = s;
  __syncthreads();
  for (int off = 1; off < 256; off <<= 1) {
    int v = (tid >= off) ? sp[tid - off] : 0;
    __syncthreads();
    sp[tid] += v;
    __syncthreads();
  }
  int run = (tid > 0) ? sp[tid - 1] : 0;
  for (int j = 0; j < 4; ++j) {
    int t = i0 + j;
    if (t < NBINS) bin_start[t] = run;
    run += sb[t];
  }
  if (tid == 255) bin_start[NBINS] = sp[255];
}

// per-bin column scan over NCON=512 block columns
__global__ __launch_bounds__(512) void ks2(const int* __restrict__ bin_start,
                                           int* h_all) {
  __shared__ int sp[512];
  int b = blockIdx.x;
  int tid = threadIdx.x;
  int v = h_all[b * NCON + tid];
  sp[tid] = v;
  __syncthreads();
  for (int off = 1; off < 512; off <<= 1) {
    int t = (tid >= off) ? sp[tid - off] : 0;
    __syncthreads();
    sp[tid] += t;
    __syncthreads();
  }
  h_all[b * NCON + tid] = bin_start[b] + sp[tid] - v;  // exclusive
}

// single-pass scatter with exact precomputed per-(block,bin) bases;
// ONE plain cached 8B store per edge
__global__ __launch_bounds__(CON_T) void kc(const int* __restrict__ aes,
                                            const int* __restrict__ aed,
                                            const float* __restrict__ aw,
                                            int E_a,
                                            const int* __restrict__ h_all,
                                            u2v* __restrict__ csr) {
  __shared__ int cur[NBINS];
  for (int b = threadIdx.x; b < NBINS; b += CON_T)
    cur[b] = h_all[b * NCON + blockIdx.x];
  __syncthreads();
  const i4v* aed4 = (const i4v*)aed;
  const i4v* aes4 = (const i4v*)aes;
  const f4v* aw4 = (const f4v*)aw;
  int nv4 = E_a >> 2;
  int stride = gridDim.x * CON_T;
  for (int v = blockIdx.x * CON_T + (int)threadIdx.x; v < nv4; v += stride) {
    i4v d4 = aed4[v];  // L3-hot from kh
    i4v s4 = __builtin_nontemporal_load(&aes4[v]);
    f4v w4 = __builtin_nontemporal_load(&aw4[v]);
#pragma unroll
    for (int j = 0; j < 4; ++j) {
      int d = d4[j] - ASS0;
      int pos = atomicAdd(&cur[d >> 8], 1);
      u2v q;
      q.x = ((unsigned)s4[j] << 8) | (unsigned)(d & 255);
      q.y = __float_as_uint(w4[j]);
      csr[pos] = q;
    }
  }
  if (blockIdx.x == 0) {
    for (int e = (nv4 << 2) + (int)threadIdx.x; e < E_a; e += CON_T) {
      int d = aed[e] - ASS0;
      int pos = atomicAdd(&cur[d >> 8], 1);
      u2v q;
      q.x = ((unsigned)aes[e] << 8) | (unsigned)(d & 255);
      q.y = __float_as_uint(aw[e]);
      csr[pos] = q;
    }
  }
}

// one propagation round; grid = NBINS blocks x 1024 threads; 4x unrolled
__global__ __launch_bounds__(KR_T) void kR(int r, int* flags,
                                           const int* __restrict__ bin_start,
                                           const u2v* __restrict__ csr,
                                           float* __restrict__ mem,
                                           u2v* __restrict__ ltv) {
  if (r > 0 && flags[r] == 0) return;  // uniform: empty round is a no-op
  __shared__ float slice[BIN_SZ];
  __shared__ int smask[BIN_SZ];
  __shared__ int newfront;
  int tid = threadIdx.x;
  int bin = blockIdx.x;
  if (tid < BIN_SZ) {
    slice[tid] = 0.f;
    smask[tid] = 0;
  }
  if (tid == 0) newfront = 0;
  __syncthreads();
  int e0 = bin_start[bin], e1 = bin_start[bin + 1];
  unsigned rl = (unsigned)r;
  int e = e0 + tid;
  // 4x unrolled main loop: batch 4 stream loads, then 4 gathers (MLP)
  for (; e + 3 * KR_T < e1; e += 4 * KR_T) {
    u2v q0 = __builtin_nontemporal_load(&csr[e]);
    u2v q1 = __builtin_nontemporal_load(&csr[e + KR_T]);
    u2v q2 = __builtin_nontemporal_load(&csr[e + 2 * KR_T]);
    u2v q3 = __builtin_nontemporal_load(&csr[e + 3 * KR_T]);
    u2v l0 = ltv[q0.x >> 8];
    u2v l1 = ltv[q1.x >> 8];
    u2v l2 = ltv[q2.x >> 8];
    u2v l3 = ltv[q3.x >> 8];
    if (l0.x == rl) {
      atomicAdd(&slice[q0.x & 255],
                __uint_as_float(l0.y) * __uint_as_float(q0.y));
      smask[q0.x & 255] = 1;
    }
    if (l1.x == rl) {
      atomicAdd(&slice[q1.x & 255],
                __uint_as_float(l1.y) * __uint_as_float(q1.y));
      smask[q1.x & 255] = 1;
    }
    if (l2.x == rl) {
      atomicAdd(&slice[q2.x & 255],
                __uint_as_float(l2.y) * __uint_as_float(q2.y));
      smask[q2.x & 255] = 1;
    }
    if (l3.x == rl) {
      atomicAdd(&slice[q3.x & 255],
                __uint_as_float(l3.y) * __uint_as_float(q3.y));
      smask[q3.x & 255] = 1;
    }
  }
  for (; e < e1; e += KR_T) {
    u2v q = __builtin_nontemporal_load(&csr[e]);
    u2v lt = ltv[q.x >> 8];
    if (lt.x == rl) {
      atomicAdd(&slice[q.x & 255],
                __uint_as_float(lt.y) * __uint_as_float(q.y));
      smask[q.x & 255] = 1;
    }
  }
  __syncthreads();
  if (tid < BIN_SZ) {
    int d = bin * BIN_SZ + tid;
    if (d < NDST && smask[tid]) {
      int node = ASS0 + d;
      float nv = mem[node] + slice[tid];
      u2v lt = ltv[node];  // only this block ever writes this node's ltv
      if (lt.x == 255u) {  // first receipt: becomes working, fires next round
        u2v nl;
        nl.x = (unsigned)(r + 1);
        if (node < OUT0) {
          nl.y = __float_as_uint(tanhf(nv));  // snapshot at fire time
          ltv[node] = nl;
          mem[node] = 0.f;  // fired neurons erase memory
          newfront = 1;     // benign LDS race
        } else {
          nl.y = 0u;
          ltv[node] = nl;
          mem[node] = nv;  // outputs never fire, just accumulate
        }
      } else {
        mem[node] = nv;  // already fired/working: keep accumulating
      }
    }
  }
  __syncthreads();
  if (tid == 0 && newfront) flags[r + 1] = 1;
}

__global__ __launch_bounds__(256) void ko(const float* __restrict__ mem,
                                          float* __restrict__ out) {
  int i = blockIdx.x * 256 + threadIdx.x;
  if (i < OUT_F) out[i] = tanhf(mem[OUT0 + i]);
}

// ---------------------------------------------------------------------------
// Fallback dense multi-kernel path if ws too small.
// ---------------------------------------------------------------------------

__global__ __launch_bounds__(256) void k_init(float* mem, float* delta,
                                              int* status, int* got) {
  int i = blockIdx.x * 256 + threadIdx.x;
  if (i < TOTAL) {
    mem[i] = 0.f;
    delta[i] = 0.f;
    status[i] = 0;
    got[i] = 0;
  }
}
__global__ __launch_bounds__(256) void k_input(const float* __restrict__ x,
                                               const float* __restrict__ w,
                                               const int* __restrict__ src,
                                               const int* __restrict__ dst,
                                               int n, float* mem, int* got) {
  for (int e = blockIdx.x * 256 + threadIdx.x; e < n; e += gridDim.x * 256) {
    atomicAdd(&mem[dst[e]], x[src[e]] * w[e]);
    got[dst[e]] = 1;
  }
}
__global__ __launch_bounds__(256) void k_status0(int* status, int* got) {
  int i = blockIdx.x * 256 + threadIdx.x;
  if (i < TOTAL) {
    status[i] = got[i] ? 1 : 0;
    got[i] = 0;
  }
}
__global__ __launch_bounds__(256) void k_edge(const float* __restrict__ w,
                                              const int* __restrict__ src,
                                              const int* __restrict__ dst,
                                              int n,
                                              const float* __restrict__ mem,
                                              const int* __restrict__ status,
                                              float* delta, int* got) {
  for (int e = blockIdx.x * 256 + threadIdx.x; e < n; e += gridDim.x * 256) {
    int s = src[e];
    if (status[s] == 1) {
      atomicAdd(&delta[dst[e]], tanhf(mem[s]) * w[e]);
      got[dst[e]] = 1;
    }
  }
}
__global__ __launch_bounds__(256) void k_update(float* mem, float* delta,
                                                int* status, int* got) {
  int i = blockIdx.x * 256 + threadIdx.x;
  if (i < TOTAL) {
    int st = status[i];
    bool fire = (st == 1) && (i >= ASS0) && (i < OUT0);
    float d = delta[i];
    mem[i] = fire ? d : (mem[i] + d);
    status[i] = fire ? 2 : ((got[i] && st == 0) ? 1 : st);
    delta[i] = 0.f;
    got[i] = 0;
  }
}

extern "C" void kernel_launch(void* const* d_in, const int* in_sizes, int n_in,
                              void* d_out, int out_size, void* d_ws,
                              size_t ws_size, hipStream_t stream) {
  const float* x = (const float*)d_in[0];
  const float* iw = (const float*)d_in[1];
  const float* aw = (const float*)d_in[2];
  const int* ies = (const int*)d_in[3];
  const int* ied = (const int*)d_in[4];
  const int* aes = (const int*)d_in[5];
  const int* aed = (const int*)d_in[6];
  int E_in = in_sizes[1];
  int E_a = in_sizes[2];
  float* out = (float*)d_out;
  char* ws = (char*)d_ws;

  // layout (8B-aligned first): csr | ltv | mem | h_all | bin_count |
  //   bin_start | flags
  size_t off_csr = 0;
  size_t off_ltv = off_csr + (size_t)E_a * 8;
  size_t off_mem = off_ltv + (size_t)TOTAL * 8;
  size_t off_hall = off_mem + (size_t)TOTAL * 4;
  size_t off_bcnt = off_hall + (size_t)NBINS * NCON * 4;
  size_t off_bst = off_bcnt + (size_t)NBINS * 4;
  size_t off_flags = off_bst + (size_t)(NBINS + 1) * 4;
  size_t need = off_flags + 32 * 4;

  if (ws_size >= need) {
    u2v* csr = (u2v*)(ws + off_csr);
    u2v* ltv = (u2v*)(ws + off_ltv);
    float* mem = (float*)(ws + off_mem);
    int* h_all = (int*)(ws + off_hall);
    int* bin_count = (int*)(ws + off_bcnt);
    int* bin_start = (int*)(ws + off_bst);
    int* flags = (int*)(ws + off_flags);

    kz<<<(TOTAL + 255) / 256, 256, 0, stream>>>(mem, ltv, flags, bin_count);
    ki<<<(E_in + 255) / 256, 256, 0, stream>>>(x, iw, ies, ied, E_in, mem,
                                               (unsigned int*)ltv);
    kp<<<(ASS + 255) / 256, 256, 0, stream>>>(mem, ltv);
    kh<<<NCON, CON_T, 0, stream>>>(aed, E_a, h_all, bin_count);
    ks<<<1, 256, 0, stream>>>(bin_count, bin_start);
    ks2<<<NBINS, 512, 0, stream>>>(bin_start, h_all);
    kc<<<NCON, CON_T, 0, stream>>>(aes, aed, aw, E_a, h_all, csr);

    for (int r = 0; r < NUM_ROUNDS; ++r)
      kR<<<NBINS, KR_T, 0, stream>>>(r, flags, bin_start, csr, mem, ltv);

    ko<<<(OUT_F + 255) / 256, 256, 0, stream>>>(mem, out);
    return;
  }

  // fallback: dense path
  float* mem = (float*)ws;
  float* delta = mem + TOTAL;
  int* status = (int*)(delta + TOTAL);
  int* got = status + TOTAL;
  const int nodeBlocks = (TOTAL + 255) / 256;
  k_init<<<nodeBlocks, 256, 0, stream>>>(mem, delta, status, got);
  int inBlocks = (E_in + 255) / 256;
  if (inBlocks > 1024) inBlocks = 1024;
  k_input<<<inBlocks, 256, 0, stream>>>(x, iw, ies, ied, E_in, mem, got);
  k_status0<<<nodeBlocks, 256, 0, stream>>>(status, got);
  int eBlocks = (E_a + 255) / 256;
  if (eBlocks > 2048) eBlocks = 2048;
  for (int r = 0; r < NUM_ROUNDS; ++r) {
    k_edge<<<eBlocks, 256, 0, stream>>>(aw, aes, aed, E_a, mem, status, delta,
                                        got);
    k_update<<<nodeBlocks, 256, 0, stream>>>(mem, delta, status, got);
  }
  ko<<<(OUT_F + 255) / 256, 256, 0, stream>>>(mem, out);
}

// Round 13
// 192.417 us; speedup vs baseline: 1.8579x; 1.0086x over previous
//
#include <hip/hip_runtime.h>
#include <hip/hip_cooperative_groups.h>

namespace cg = cooperative_groups;

#define IN_F 1024
#define ASS 100000
#define OUT_F 1024
#define TOTAL (IN_F + ASS + OUT_F)  // 102048
#define ASS0 IN_F
#define OUT0 (IN_F + ASS)
#define NDST (ASS + OUT_F)  // 101024 destinations, node = ASS0 + d
#define NUM_ROUNDS 24

#define BIN_SZ 512  // dst nodes per bin
#define BIN_SH 9
#define BIN_MK 511
#define NBINS ((NDST + BIN_SZ - 1) / BIN_SZ)  // 198
#define NCON 512    // construction blocks
#define CON_T 1024  // construction threads per block
#define SPLIT 8     // sub-blocks per bin in split rounds
#define NSPLIT_R 4  // rounds 0..3 use the split path

typedef int i4v __attribute__((ext_vector_type(4)));
typedef float f4v __attribute__((ext_vector_type(4)));
typedef unsigned int u2v __attribute__((ext_vector_type(2)));

// ---------------------------------------------------------------------------
// Each assoc neuron fires exactly once at BFS level L(u).
// csr[e] = {src<<9 | dstoff, w} packed 8B (one cached 8B scattered store in
// kc; NT scatter measured 2.1x worse). ltv[node] = {lev, tanh snapshot}
// packed 8B: one gather per edge. BIN_SZ=512 doubles kc's per-(block,bin)
// segment -> fewer boundary-line double writes, cursor lines L2-resident.
// Rounds 0..3 (heavy): kRe (NBINS*8 blocks, LDS partial slices -> gslice) +
// kRn (merge 8 partials + epilogue). Kernel boundaries order everything.
// Rounds 4..23: one cooperative kTail, grid.sync per round, instant uniform
// exit once the frontier is empty (normally immediately).
// Torn-8B-read safety: ltv writes only transition lev 255->r+1, so a reader
// checking lev==r can never pair a stale tv with a matching lev.
// ---------------------------------------------------------------------------

__global__ __launch_bounds__(256) void kz(float* mem, u2v* ltv, int* flags,
                                          int* bin_count) {
  int i = blockIdx.x * 256 + threadIdx.x;
  int gs = gridDim.x * 256;
  u2v init;
  init.x = 255u;
  init.y = 0u;
  for (int k = i; k < TOTAL; k += gs) {
    mem[k] = 0.f;
    ltv[k] = init;
  }
  for (int k = i; k < NBINS; k += gs) bin_count[k] = 0;
  if (i < 32) flags[i] = 0;
}

__global__ __launch_bounds__(256) void ki(const float* __restrict__ x,
                                          const float* __restrict__ iw,
                                          const int* __restrict__ ies,
                                          const int* __restrict__ ied, int E_in,
                                          float* mem, unsigned int* ltv_raw) {
  int e = blockIdx.x * 256 + threadIdx.x;
  if (e < E_in) {
    int d = ied[e];
    atomicAdd(&mem[d], x[ies[e]] * iw[e]);
    ltv_raw[2 * d] = 0u;  // lev = 0; benign race, all writers store 0
  }
}

// snapshot level-0 frontier: tv = tanh(mem), mem = 0
__global__ __launch_bounds__(256) void kp(float* mem, u2v* ltv) {
  int i = blockIdx.x * 256 + threadIdx.x;
  if (i < ASS) {
    int node = ASS0 + i;
    u2v lt = ltv[node];
    if (lt.x == 0u) {
      lt.y = __float_as_uint(tanhf(mem[node]));
      ltv[node] = lt;
      mem[node] = 0.f;
    }
  }
}

// per-block histogram -> h_all[bin*NCON + block]; totals -> bin_count
// dual LDS copies halve same-address atomic conflicts; cached aed loads
// leave it L3-hot for kc
__global__ __launch_bounds__(CON_T) void kh(const int* __restrict__ aed,
                                            int E_a, int* h_all,
                                            int* bin_count) {
  __shared__ int h[2][NBINS];
  for (int b = threadIdx.x; b < 2 * NBINS; b += CON_T) h[b / NBINS][b % NBINS] = 0;
  __syncthreads();
  int cp = (threadIdx.x >> 6) & 1;
  const i4v* aed4 = (const i4v*)aed;
  int nv4 = E_a >> 2;
  int stride = gridDim.x * CON_T;
  for (int v = blockIdx.x * CON_T + (int)threadIdx.x; v < nv4; v += stride) {
    i4v d4 = aed4[v];
    atomicAdd(&h[cp][(d4.x - ASS0) >> BIN_SH], 1);
    atomicAdd(&h[cp][(d4.y - ASS0) >> BIN_SH], 1);
    atomicAdd(&h[cp][(d4.z - ASS0) >> BIN_SH], 1);
    atomicAdd(&h[cp][(d4.w - ASS0) >> BIN_SH], 1);
  }
  if (blockIdx.x == 0) {
    for (int e = (nv4 << 2) + (int)threadIdx.x; e < E_a; e += CON_T)
      atomicAdd(&h[cp][(aed[e] - ASS0) >> BIN_SH], 1);
  }
  __syncthreads();
  for (int b = threadIdx.x; b < NBINS; b += CON_T) {
    int c = h[0][b] + h[1][b];
    h_all[b * NCON + blockIdx.x] = c;
    if (c) atomicAdd(&bin_count[b], c);
  }
}

// exclusive scan of bin counts (single block; NBINS <= 256)
__global__ __launch_bounds__(256) void ks(const int* __restrict__ bin_count,
                                          int* bin_start) {
  __shared__ int sp[256];
  int tid = threadIdx.x;
  int v = (tid < NBINS) ? bin_count[tid] : 0;
  sp[tid] = v;
  __syncthreads();
  for (int off = 1; off < 256; off <<= 1) {
    int t = (tid >= off) ? sp[tid - off] : 0;
    __syncthreads();
    sp[tid] += t;
    __syncthreads();
  }
  if (tid < NBINS) bin_start[tid] = sp[tid] - v;
  if (tid == 255) bin_start[NBINS] = sp[255];
}

// per-bin column scan over NCON=512 block columns
__global__ __launch_bounds__(512) void ks2(const int* __restrict__ bin_start,
                                           int* h_all) {
  __shared__ int sp[512];
  int b = blockIdx.x;
  int tid = threadIdx.x;
  int v = h_all[b * NCON + tid];
  sp[tid] = v;
  __syncthreads();
  for (int off = 1; off < 512; off <<= 1) {
    int t = (tid >= off) ? sp[tid - off] : 0;
    __syncthreads();
    sp[tid] += t;
    __syncthreads();
  }
  h_all[b * NCON + tid] = bin_start[b] + sp[tid] - v;  // exclusive
}

// single-pass scatter with exact precomputed per-(block,bin) bases;
// ONE plain cached 8B store per edge
__global__ __launch_bounds__(CON_T) void kc(const int* __restrict__ aes,
                                            const int* __restrict__ aed,
                                            const float* __restrict__ aw,
                                            int E_a,
                                            const int* __restrict__ h_all,
                                            u2v* __restrict__ csr) {
  __shared__ int cur[NBINS];
  for (int b = threadIdx.x; b < NBINS; b += CON_T)
    cur[b] = h_all[b * NCON + blockIdx.x];
  __syncthreads();
  const i4v* aed4 = (const i4v*)aed;
  const i4v* aes4 = (const i4v*)aes;
  const f4v* aw4 = (const f4v*)aw;
  int nv4 = E_a >> 2;
  int stride = gridDim.x * CON_T;
  for (int v = blockIdx.x * CON_T + (int)threadIdx.x; v < nv4; v += stride) {
    i4v d4 = aed4[v];  // L3-hot from kh
    i4v s4 = __builtin_nontemporal_load(&aes4[v]);
    f4v w4 = __builtin_nontemporal_load(&aw4[v]);
#pragma unroll
    for (int j = 0; j < 4; ++j) {
      int d = d4[j] - ASS0;
      int pos = atomicAdd(&cur[d >> BIN_SH], 1);
      u2v q;
      q.x = ((unsigned)s4[j] << BIN_SH) | (unsigned)(d & BIN_MK);
      q.y = __float_as_uint(w4[j]);
      csr[pos] = q;
    }
  }
  if (blockIdx.x == 0) {
    for (int e = (nv4 << 2) + (int)threadIdx.x; e < E_a; e += CON_T) {
      int d = aed[e] - ASS0;
      int pos = atomicAdd(&cur[d >> BIN_SH], 1);
      u2v q;
      q.x = ((unsigned)aes[e] << BIN_SH) | (unsigned)(d & BIN_MK);
      q.y = __float_as_uint(aw[e]);
      csr[pos] = q;
    }
  }
}

// split-round edge pass: grid NBINS*SPLIT x 256; partial slices -> global
__global__ __launch_bounds__(256) void kRe(int r, const int* __restrict__ flags,
                                           const int* __restrict__ bin_start,
                                           const u2v* __restrict__ csr,
                                           const u2v* __restrict__ ltv,
                                           float* __restrict__ gslice,
                                           char* __restrict__ gmask) {
  if (r > 0 && flags[r] == 0) return;
  __shared__ float slice[BIN_SZ];
  __shared__ int smask[BIN_SZ];
  int tid = threadIdx.x;
  int bin = blockIdx.x >> 3;  // SPLIT == 8
  int sub = blockIdx.x & (SPLIT - 1);
  for (int i = tid; i < BIN_SZ; i += 256) {
    slice[i] = 0.f;
    smask[i] = 0;
  }
  __syncthreads();
  int e0 = bin_start[bin], e1 = bin_start[bin + 1];
  int len = e1 - e0;
  int chunk = (len + SPLIT - 1) / SPLIT;
  int s0 = e0 + sub * chunk;
  int s1 = min(s0 + chunk, e1);
  unsigned rl = (unsigned)r;
  int e = s0 + tid;
  for (; e + 3 * 256 < s1; e += 4 * 256) {
    u2v q0 = __builtin_nontemporal_load(&csr[e]);
    u2v q1 = __builtin_nontemporal_load(&csr[e + 256]);
    u2v q2 = __builtin_nontemporal_load(&csr[e + 512]);
    u2v q3 = __builtin_nontemporal_load(&csr[e + 768]);
    u2v l0 = ltv[q0.x >> BIN_SH];
    u2v l1 = ltv[q1.x >> BIN_SH];
    u2v l2 = ltv[q2.x >> BIN_SH];
    u2v l3 = ltv[q3.x >> BIN_SH];
    if (l0.x == rl) {
      atomicAdd(&slice[q0.x & BIN_MK],
                __uint_as_float(l0.y) * __uint_as_float(q0.y));
      smask[q0.x & BIN_MK] = 1;
    }
    if (l1.x == rl) {
      atomicAdd(&slice[q1.x & BIN_MK],
                __uint_as_float(l1.y) * __uint_as_float(q1.y));
      smask[q1.x & BIN_MK] = 1;
    }
    if (l2.x == rl) {
      atomicAdd(&slice[q2.x & BIN_MK],
                __uint_as_float(l2.y) * __uint_as_float(q2.y));
      smask[q2.x & BIN_MK] = 1;
    }
    if (l3.x == rl) {
      atomicAdd(&slice[q3.x & BIN_MK],
                __uint_as_float(l3.y) * __uint_as_float(q3.y));
      smask[q3.x & BIN_MK] = 1;
    }
  }
  for (; e < s1; e += 256) {
    u2v q = __builtin_nontemporal_load(&csr[e]);
    u2v lt = ltv[q.x >> BIN_SH];
    if (lt.x == rl) {
      atomicAdd(&slice[q.x & BIN_MK],
                __uint_as_float(lt.y) * __uint_as_float(q.y));
      smask[q.x & BIN_MK] = 1;
    }
  }
  __syncthreads();
  int base = blockIdx.x * BIN_SZ;
  for (int i = tid; i < BIN_SZ; i += 256) {
    gslice[base + i] = slice[i];
    gmask[base + i] = (char)smask[i];
  }
}

// split-round node pass: merge SPLIT partials + epilogue; grid NBINS x 512
__global__ __launch_bounds__(512) void kRn(int r, int* flags,
                                           const float* __restrict__ gslice,
                                           const char* __restrict__ gmask,
                                           float* __restrict__ mem,
                                           u2v* __restrict__ ltv) {
  if (r > 0 && flags[r] == 0) return;
  __shared__ int newfront;
  int tid = threadIdx.x;
  int bin = blockIdx.x;
  if (tid == 0) newfront = 0;
  __syncthreads();
  float sv = 0.f;
  int mk = 0;
  int base = bin * SPLIT * BIN_SZ + tid;
#pragma unroll
  for (int s = 0; s < SPLIT; ++s) {
    sv += gslice[base + s * BIN_SZ];
    mk |= (int)gmask[base + s * BIN_SZ];
  }
  int d = bin * BIN_SZ + tid;
  if (d < NDST && mk) {
    int node = ASS0 + d;
    float nv = mem[node] + sv;
    u2v lt = ltv[node];  // only this block ever writes this node's ltv
    if (lt.x == 255u) {  // first receipt: becomes working, fires next round
      u2v nl;
      nl.x = (unsigned)(r + 1);
      if (node < OUT0) {
        nl.y = __float_as_uint(tanhf(nv));  // snapshot at fire time
        ltv[node] = nl;
        mem[node] = 0.f;  // fired neurons erase memory
        newfront = 1;     // benign LDS race
      } else {
        nl.y = 0u;
        ltv[node] = nl;
        mem[node] = nv;  // outputs never fire, just accumulate
      }
    } else {
      mem[node] = nv;
    }
  }
  __syncthreads();
  if (tid == 0 && newfront) flags[r + 1] = 1;
}

// fused single round (fallback path B); grid NBINS x 1024
__global__ __launch_bounds__(1024) void kRf(int r, int* flags,
                                            const int* __restrict__ bin_start,
                                            const u2v* __restrict__ csr,
                                            float* __restrict__ mem,
                                            u2v* __restrict__ ltv) {
  if (r > 0 && flags[r] == 0) return;
  __shared__ float slice[BIN_SZ];
  __shared__ int smask[BIN_SZ];
  __shared__ int newfront;
  int tid = threadIdx.x;
  int bin = blockIdx.x;
  if (tid < BIN_SZ) {
    slice[tid] = 0.f;
    smask[tid] = 0;
  }
  if (tid == 0) newfront = 0;
  __syncthreads();
  int e0 = bin_start[bin], e1 = bin_start[bin + 1];
  unsigned rl = (unsigned)r;
  int e = e0 + tid;
  for (; e + 3 * 1024 < e1; e += 4 * 1024) {
    u2v q0 = __builtin_nontemporal_load(&csr[e]);
    u2v q1 = __builtin_nontemporal_load(&csr[e + 1024]);
    u2v q2 = __builtin_nontemporal_load(&csr[e + 2048]);
    u2v q3 = __builtin_nontemporal_load(&csr[e + 3072]);
    u2v l0 = ltv[q0.x >> BIN_SH];
    u2v l1 = ltv[q1.x >> BIN_SH];
    u2v l2 = ltv[q2.x >> BIN_SH];
    u2v l3 = ltv[q3.x >> BIN_SH];
    if (l0.x == rl) {
      atomicAdd(&slice[q0.x & BIN_MK],
                __uint_as_float(l0.y) * __uint_as_float(q0.y));
      smask[q0.x & BIN_MK] = 1;
    }
    if (l1.x == rl) {
      atomicAdd(&slice[q1.x & BIN_MK],
                __uint_as_float(l1.y) * __uint_as_float(q1.y));
      smask[q1.x & BIN_MK] = 1;
    }
    if (l2.x == rl) {
      atomicAdd(&slice[q2.x & BIN_MK],
                __uint_as_float(l2.y) * __uint_as_float(q2.y));
      smask[q2.x & BIN_MK] = 1;
    }
    if (l3.x == rl) {
      atomicAdd(&slice[q3.x & BIN_MK],
                __uint_as_float(l3.y) * __uint_as_float(q3.y));
      smask[q3.x & BIN_MK] = 1;
    }
  }
  for (; e < e1; e += 1024) {
    u2v q = __builtin_nontemporal_load(&csr[e]);
    u2v lt = ltv[q.x >> BIN_SH];
    if (lt.x == rl) {
      atomicAdd(&slice[q.x & BIN_MK],
                __uint_as_float(lt.y) * __uint_as_float(q.y));
      smask[q.x & BIN_MK] = 1;
    }
  }
  __syncthreads();
  if (tid < BIN_SZ) {
    int d = bin * BIN_SZ + tid;
    if (d < NDST && smask[tid]) {
      int node = ASS0 + d;
      float nv = mem[node] + slice[tid];
      u2v lt = ltv[node];
      if (lt.x == 255u) {
        u2v nl;
        nl.x = (unsigned)(r + 1);
        if (node < OUT0) {
          nl.y = __float_as_uint(tanhf(nv));
          ltv[node] = nl;
          mem[node] = 0.f;
          newfront = 1;
        } else {
          nl.y = 0u;
          ltv[node] = nl;
          mem[node] = nv;
        }
      } else {
        mem[node] = nv;
      }
    }
  }
  __syncthreads();
  if (tid == 0 && newfront) flags[r + 1] = 1;
}

// tail rounds 4..23 in ONE cooperative kernel; exits the moment a round is
// empty (normally immediately). 198 blocks trivially co-resident.
__global__ __launch_bounds__(1024) void kTail(int* flags,
                                              const int* __restrict__ bin_start,
                                              const u2v* __restrict__ csr,
                                              float* __restrict__ mem,
                                              u2v* __restrict__ ltv) {
  cg::grid_group g = cg::this_grid();
  __shared__ float slice[BIN_SZ];
  __shared__ int smask[BIN_SZ];
  __shared__ int newfront;
  int tid = threadIdx.x;
  int bin = blockIdx.x;
  int e0 = bin_start[bin], e1 = bin_start[bin + 1];
  for (int r = NSPLIT_R; r < NUM_ROUNDS; ++r) {
    if (flags[r] == 0) return;  // uniform across grid
    if (tid < BIN_SZ) {
      slice[tid] = 0.f;
      smask[tid] = 0;
    }
    if (tid == 0) newfront = 0;
    __syncthreads();
    unsigned rl = (unsigned)r;
    for (int e = e0 + tid; e < e1; e += 1024) {
      u2v q = __builtin_nontemporal_load(&csr[e]);
      u2v lt = ltv[q.x >> BIN_SH];
      if (lt.x == rl) {
        atomicAdd(&slice[q.x & BIN_MK],
                  __uint_as_float(lt.y) * __uint_as_float(q.y));
        smask[q.x & BIN_MK] = 1;
      }
    }
    __syncthreads();
    if (tid < BIN_SZ) {
      int d = bin * BIN_SZ + tid;
      if (d < NDST && smask[tid]) {
        int node = ASS0 + d;
        float nv = mem[node] + slice[tid];
        u2v lt = ltv[node];
        if (lt.x == 255u) {
          u2v nl;
          nl.x = (unsigned)(r + 1);
          if (node < OUT0) {
            nl.y = __float_as_uint(tanhf(nv));
            ltv[node] = nl;
            mem[node] = 0.f;
            newfront = 1;
          } else {
            nl.y = 0u;
            ltv[node] = nl;
            mem[node] = nv;
          }
        } else {
          mem[node] = nv;
        }
      }
    }
    __syncthreads();
    if (tid == 0 && newfront) flags[r + 1] = 1;
    g.sync();
  }
}

__global__ __launch_bounds__(256) void ko(const float* __restrict__ mem,
                                          float* __restrict__ out) {
  int i = blockIdx.x * 256 + threadIdx.x;
  if (i < OUT_F) out[i] = tanhf(mem[OUT0 + i]);
}

// ---------------------------------------------------------------------------
// Fallback dense multi-kernel path if ws too small.
// ---------------------------------------------------------------------------

__global__ __launch_bounds__(256) void k_init(float* mem, float* delta,
                                              int* status, int* got) {
  int i = blockIdx.x * 256 + threadIdx.x;
  if (i < TOTAL) {
    mem[i] = 0.f;
    delta[i] = 0.f;
    status[i] = 0;
    got[i] = 0;
  }
}
__global__ __launch_bounds__(256) void k_input(const float* __restrict__ x,
                                               const float* __restrict__ w,
                                               const int* __restrict__ src,
                                               const int* __restrict__ dst,
                                               int n, float* mem, int* got) {
  for (int e = blockIdx.x * 256 + threadIdx.x; e < n; e += gridDim.x * 256) {
    atomicAdd(&mem[dst[e]], x[src[e]] * w[e]);
    got[dst[e]] = 1;
  }
}
__global__ __launch_bounds__(256) void k_status0(int* status, int* got) {
  int i = blockIdx.x * 256 + threadIdx.x;
  if (i < TOTAL) {
    status[i] = got[i] ? 1 : 0;
    got[i] = 0;
  }
}
__global__ __launch_bounds__(256) void k_edge(const float* __restrict__ w,
                                              const int* __restrict__ src,
                                              const int* __restrict__ dst,
                                              int n,
                                              const float* __restrict__ mem,
                                              const int* __restrict__ status,
                                              float* delta, int* got) {
  for (int e = blockIdx.x * 256 + threadIdx.x; e < n; e += gridDim.x * 256) {
    int s = src[e];
    if (status[s] == 1) {
      atomicAdd(&delta[dst[e]], tanhf(mem[s]) * w[e]);
      got[dst[e]] = 1;
    }
  }
}
__global__ __launch_bounds__(256) void k_update(float* mem, float* delta,
                                                int* status, int* got) {
  int i = blockIdx.x * 256 + threadIdx.x;
  if (i < TOTAL) {
    int st = status[i];
    bool fire = (st == 1) && (i >= ASS0) && (i < OUT0);
    float d = delta[i];
    mem[i] = fire ? d : (mem[i] + d);
    status[i] = fire ? 2 : ((got[i] && st == 0) ? 1 : st);
    delta[i] = 0.f;
    got[i] = 0;
  }
}

extern "C" void kernel_launch(void* const* d_in, const int* in_sizes, int n_in,
                              void* d_out, int out_size, void* d_ws,
                              size_t ws_size, hipStream_t stream) {
  const float* x = (const float*)d_in[0];
  const float* iw = (const float*)d_in[1];
  const float* aw = (const float*)d_in[2];
  const int* ies = (const int*)d_in[3];
  const int* ied = (const int*)d_in[4];
  const int* aes = (const int*)d_in[5];
  const int* aed = (const int*)d_in[6];
  int E_in = in_sizes[1];
  int E_a = in_sizes[2];
  float* out = (float*)d_out;
  char* ws = (char*)d_ws;

  // layout: csr | ltv | mem | h_all | bin_count | bin_start | flags |
  //         gslice | gmask
  size_t off_csr = 0;
  size_t off_ltv = off_csr + (size_t)E_a * 8;
  size_t off_mem = off_ltv + (size_t)TOTAL * 8;
  size_t off_hall = off_mem + (size_t)TOTAL * 4;
  size_t off_bcnt = off_hall + (size_t)NBINS * NCON * 4;
  size_t off_bst = off_bcnt + (size_t)NBINS * 4;
  size_t off_flags = off_bst + (size_t)(NBINS + 1) * 4;
  size_t off_gsl = off_flags + 32 * 4;
  size_t off_gmk = off_gsl + (size_t)NBINS * SPLIT * BIN_SZ * 4;
  size_t needA = off_gmk + (size_t)NBINS * SPLIT * BIN_SZ;
  size_t needB = off_gsl;

  if (ws_size >= needB) {
    u2v* csr = (u2v*)(ws + off_csr);
    u2v* ltv = (u2v*)(ws + off_ltv);
    float* mem = (float*)(ws + off_mem);
    int* h_all = (int*)(ws + off_hall);
    int* bin_count = (int*)(ws + off_bcnt);
    int* bin_start = (int*)(ws + off_bst);
    int* flags = (int*)(ws + off_flags);
    float* gslice = (float*)(ws + off_gsl);
    char* gmask = ws + off_gmk;

    kz<<<(TOTAL + 255) / 256, 256, 0, stream>>>(mem, ltv, flags, bin_count);
    ki<<<(E_in + 255) / 256, 256, 0, stream>>>(x, iw, ies, ied, E_in, mem,
                                               (unsigned int*)ltv);
    kp<<<(ASS + 255) / 256, 256, 0, stream>>>(mem, ltv);
    kh<<<NCON, CON_T, 0, stream>>>(aed, E_a, h_all, bin_count);
    ks<<<1, 256, 0, stream>>>(bin_count, bin_start);
    ks2<<<NBINS, 512, 0, stream>>>(bin_start, h_all);
    kc<<<NCON, CON_T, 0, stream>>>(aes, aed, aw, E_a, h_all, csr);

    if (ws_size >= needA) {
      for (int r = 0; r < NSPLIT_R; ++r) {
        kRe<<<NBINS * SPLIT, 256, 0, stream>>>(r, flags, bin_start, csr, ltv,
                                               gslice, gmask);
        kRn<<<NBINS, 512, 0, stream>>>(r, flags, gslice, gmask, mem, ltv);
      }
      void* targs[] = {(void*)&flags, (void*)&bin_start, (void*)&csr,
                       (void*)&mem, (void*)&ltv};
      hipLaunchCooperativeKernel((void*)kTail, dim3(NBINS), dim3(1024), targs,
                                 0, stream);
    } else {
      for (int r = 0; r < NUM_ROUNDS; ++r)
        kRf<<<NBINS, 1024, 0, stream>>>(r, flags, bin_start, csr, mem, ltv);
    }

    ko<<<(OUT_F + 255) / 256, 256, 0, stream>>>(mem, out);
    return;
  }

  // fallback: dense path
  float* mem = (float*)ws;
  float* delta = mem + TOTAL;
  int* status = (int*)(delta + TOTAL);
  int* got = status + TOTAL;
  const int nodeBlocks = (TOTAL + 255) / 256;
  k_init<<<nodeBlocks, 256, 0, stream>>>(mem, delta, status, got);
  int inBlocks = (E_in + 255) / 256;
  if (inBlocks > 1024) inBlocks = 1024;
  k_input<<<inBlocks, 256, 0, stream>>>(x, iw, ies, ied, E_in, mem, got);
  k_status0<<<nodeBlocks, 256, 0, stream>>>(status, got);
  int eBlocks = (E_a + 255) / 256;
  if (eBlocks > 2048) eBlocks = 2048;
  for (int r = 0; r < NUM_ROUNDS; ++r) {
    k_edge<<<eBlocks, 256, 0, stream>>>(aw, aes, aed, E_a, mem, status, delta,
                                        got);
    k_update<<<nodeBlocks, 256, 0, stream>>>(mem, delta, status, got);
  }
  ko<<<(OUT_F + 255) / 256, 256, 0, stream>>>(mem, out);
}

// Round 14
// 163.534 us; speedup vs baseline: 2.1860x; 1.1766x over previous
//
#include <hip/hip_runtime.h>
#include <hip/hip_cooperative_groups.h>

namespace cg = cooperative_groups;

#define IN_F 1024
#define ASS 100000
#define OUT_F 1024
#define TOTAL (IN_F + ASS + OUT_F)  // 102048
#define ASS0 IN_F
#define OUT0 (IN_F + ASS)
#define NDST (ASS + OUT_F)  // 101024 destinations, node = ASS0 + d
#define NUM_ROUNDS 24

#define BIN_SZ 512  // dst nodes per bin
#define BIN_SH 9
#define BIN_MK 511
#define NBINS ((NDST + BIN_SZ - 1) / BIN_SZ)  // 198
#define NCON 512    // construction blocks
#define CON_T 1024  // construction threads per block
#define SPLIT 8     // sub-blocks per bin in split rounds (rounds 0,1)

typedef int i4v __attribute__((ext_vector_type(4)));
typedef float f4v __attribute__((ext_vector_type(4)));
typedef unsigned int u2v __attribute__((ext_vector_type(2)));

// ---------------------------------------------------------------------------
// Each assoc neuron fires exactly once at BFS level L(u).
// csr[e] = {src<<9 | dstoff, w} packed 8B in fixed-capacity per-bin regions
// (bin b occupies [b*cap, bin_cursor[b]) after construction; cap = 1.3x mean,
// ~48 sigma against overflow). Single-kernel construction kc: block-local
// histogram -> one global atomicAdd reservation per (block,bin) -> scatter.
// ltv[node] = {lev, tanh snapshot at fire time} packed 8B: one gather/edge.
// Rounds 0,1 (heavy): kRe (NBINS*8 blocks, LDS partial slices -> gslice) +
// kRn (merge 8 partials + epilogue). During round 1, kRe appends edges with
// still-unreached sources (lev==255 -- the only ones that can fire at r>=2)
// to per-bin survivor lists (~1-2% of edges). Rounds 2..23 run in ONE
// cooperative kTail over survivors (grid.sync per round, uniform early exit;
// overflow -> flags[30] -> full-csr fallback scan).
// Torn-8B-read safety: ltv writes only transition lev 255->r+1, so a reader
// checking lev==r can never pair a stale tv with a matching lev.
// ---------------------------------------------------------------------------

__global__ __launch_bounds__(256) void kz(float* mem, u2v* ltv, int* flags,
                                          int* bin_cursor, int* scur, int cap,
                                          int scap) {
  int i = blockIdx.x * 256 + threadIdx.x;
  int gs = gridDim.x * 256;
  u2v init;
  init.x = 255u;
  init.y = 0u;
  for (int k = i; k < TOTAL; k += gs) {
    mem[k] = 0.f;
    ltv[k] = init;
  }
  for (int k = i; k < NBINS; k += gs) {
    bin_cursor[k] = k * cap;
    scur[k] = k * scap;
  }
  if (i < 32) flags[i] = 0;
}

__global__ __launch_bounds__(256) void ki(const float* __restrict__ x,
                                          const float* __restrict__ iw,
                                          const int* __restrict__ ies,
                                          const int* __restrict__ ied, int E_in,
                                          float* mem, unsigned int* ltv_raw) {
  int e = blockIdx.x * 256 + threadIdx.x;
  if (e < E_in) {
    int d = ied[e];
    atomicAdd(&mem[d], x[ies[e]] * iw[e]);
    ltv_raw[2 * d] = 0u;  // lev = 0; benign race, all writers store 0
  }
}

// snapshot level-0 frontier: tv = tanh(mem), mem = 0
__global__ __launch_bounds__(256) void kp(float* mem, u2v* ltv) {
  int i = blockIdx.x * 256 + threadIdx.x;
  if (i < ASS) {
    int node = ASS0 + i;
    u2v lt = ltv[node];
    if (lt.x == 0u) {
      lt.y = __float_as_uint(tanhf(mem[node]));
      ltv[node] = lt;
      mem[node] = 0.f;
    }
  }
}

// construction: histogram chunk -> reserve global ranges -> scatter.
// aed read twice (2nd pass L2-hot); aes/aw streamed NT once.
__global__ __launch_bounds__(CON_T) void kc(const int* __restrict__ aes,
                                            const int* __restrict__ aed,
                                            const float* __restrict__ aw,
                                            int E_a, int* bin_cursor,
                                            u2v* __restrict__ csr) {
  __shared__ int h[2][NBINS];
  __shared__ int cur[NBINS];
  for (int b = threadIdx.x; b < 2 * NBINS; b += CON_T)
    h[b >= NBINS][b >= NBINS ? b - NBINS : b] = 0;
  __syncthreads();
  int cp = (threadIdx.x >> 6) & 1;
  const i4v* aed4 = (const i4v*)aed;
  const i4v* aes4 = (const i4v*)aes;
  const f4v* aw4 = (const f4v*)aw;
  int nv4 = E_a >> 2;
  int stride = gridDim.x * CON_T;
  // pass 1: local histogram
  for (int v = blockIdx.x * CON_T + (int)threadIdx.x; v < nv4; v += stride) {
    i4v d4 = aed4[v];
    atomicAdd(&h[cp][(d4.x - ASS0) >> BIN_SH], 1);
    atomicAdd(&h[cp][(d4.y - ASS0) >> BIN_SH], 1);
    atomicAdd(&h[cp][(d4.z - ASS0) >> BIN_SH], 1);
    atomicAdd(&h[cp][(d4.w - ASS0) >> BIN_SH], 1);
  }
  if (blockIdx.x == 0) {
    for (int e = (nv4 << 2) + (int)threadIdx.x; e < E_a; e += CON_T)
      atomicAdd(&h[cp][(aed[e] - ASS0) >> BIN_SH], 1);
  }
  __syncthreads();
  // reserve
  for (int b = threadIdx.x; b < NBINS; b += CON_T) {
    int c = h[0][b] + h[1][b];
    cur[b] = c ? atomicAdd(&bin_cursor[b], c) : 0;
  }
  __syncthreads();
  // pass 2: scatter
  for (int v = blockIdx.x * CON_T + (int)threadIdx.x; v < nv4; v += stride) {
    i4v d4 = aed4[v];  // L2-hot from pass 1
    i4v s4 = __builtin_nontemporal_load(&aes4[v]);
    f4v w4 = __builtin_nontemporal_load(&aw4[v]);
#pragma unroll
    for (int j = 0; j < 4; ++j) {
      int d = d4[j] - ASS0;
      int pos = atomicAdd(&cur[d >> BIN_SH], 1);
      u2v q;
      q.x = ((unsigned)s4[j] << BIN_SH) | (unsigned)(d & BIN_MK);
      q.y = __float_as_uint(w4[j]);
      csr[pos] = q;
    }
  }
  if (blockIdx.x == 0) {
    for (int e = (nv4 << 2) + (int)threadIdx.x; e < E_a; e += CON_T) {
      int d = aed[e] - ASS0;
      int pos = atomicAdd(&cur[d >> BIN_SH], 1);
      u2v q;
      q.x = ((unsigned)aes[e] << BIN_SH) | (unsigned)(d & BIN_MK);
      q.y = __float_as_uint(aw[e]);
      csr[pos] = q;
    }
  }
}

__device__ __forceinline__ void procEdge(unsigned rl, int collect, u2v q,
                                         u2v lt, float* slice, int* smask,
                                         int bin, u2v* ssur, int* scur,
                                         int* flags, int scap) {
  if (lt.x == rl) {
    atomicAdd(&slice[q.x & BIN_MK],
              __uint_as_float(lt.y) * __uint_as_float(q.y));
    smask[q.x & BIN_MK] = 1;
  } else if (collect && lt.x == 255u) {
    // source not yet reached -> only edges that can fire in rounds >= 2
    int pos = atomicAdd(&scur[bin], 1);
    if (pos < bin * scap + scap)
      ssur[pos] = q;
    else
      flags[30] = 1;  // overflow: tail falls back to full csr
  }
}

// split-round edge pass (rounds 0,1): grid NBINS*SPLIT x 256
__global__ __launch_bounds__(256) void kRe(int r, int collect, int* flags,
                                           const int* __restrict__ bin_cursor,
                                           const u2v* __restrict__ csr,
                                           const u2v* __restrict__ ltv,
                                           float* __restrict__ gslice,
                                           char* __restrict__ gmask,
                                           u2v* __restrict__ ssur, int* scur,
                                           int cap, int scap) {
  if (r > 0 && flags[r] == 0) return;
  __shared__ float slice[BIN_SZ];
  __shared__ int smask[BIN_SZ];
  int tid = threadIdx.x;
  int bin = blockIdx.x >> 3;  // SPLIT == 8
  int sub = blockIdx.x & (SPLIT - 1);
  for (int i = tid; i < BIN_SZ; i += 256) {
    slice[i] = 0.f;
    smask[i] = 0;
  }
  __syncthreads();
  int e0 = bin * cap;
  int e1 = bin_cursor[bin];
  int len = e1 - e0;
  int chunk = (len + SPLIT - 1) / SPLIT;
  int s0 = e0 + sub * chunk;
  int s1 = min(s0 + chunk, e1);
  unsigned rl = (unsigned)r;
  int e = s0 + tid;
  for (; e + 3 * 256 < s1; e += 4 * 256) {
    u2v q0 = __builtin_nontemporal_load(&csr[e]);
    u2v q1 = __builtin_nontemporal_load(&csr[e + 256]);
    u2v q2 = __builtin_nontemporal_load(&csr[e + 512]);
    u2v q3 = __builtin_nontemporal_load(&csr[e + 768]);
    u2v l0 = ltv[q0.x >> BIN_SH];
    u2v l1 = ltv[q1.x >> BIN_SH];
    u2v l2 = ltv[q2.x >> BIN_SH];
    u2v l3 = ltv[q3.x >> BIN_SH];
    procEdge(rl, collect, q0, l0, slice, smask, bin, ssur, scur, flags, scap);
    procEdge(rl, collect, q1, l1, slice, smask, bin, ssur, scur, flags, scap);
    procEdge(rl, collect, q2, l2, slice, smask, bin, ssur, scur, flags, scap);
    procEdge(rl, collect, q3, l3, slice, smask, bin, ssur, scur, flags, scap);
  }
  for (; e < s1; e += 256) {
    u2v q = __builtin_nontemporal_load(&csr[e]);
    u2v lt = ltv[q.x >> BIN_SH];
    procEdge(rl, collect, q, lt, slice, smask, bin, ssur, scur, flags, scap);
  }
  __syncthreads();
  int base = blockIdx.x * BIN_SZ;
  for (int i = tid; i < BIN_SZ; i += 256) {
    gslice[base + i] = slice[i];
    gmask[base + i] = (char)smask[i];
  }
}

// split-round node pass: merge SPLIT partials + epilogue; grid NBINS x 512
__global__ __launch_bounds__(512) void kRn(int r, int* flags,
                                           const float* __restrict__ gslice,
                                           const char* __restrict__ gmask,
                                           float* __restrict__ mem,
                                           u2v* __restrict__ ltv) {
  if (r > 0 && flags[r] == 0) return;
  __shared__ int newfront;
  int tid = threadIdx.x;
  int bin = blockIdx.x;
  if (tid == 0) newfront = 0;
  __syncthreads();
  float sv = 0.f;
  int mk = 0;
  int base = bin * SPLIT * BIN_SZ + tid;
#pragma unroll
  for (int s = 0; s < SPLIT; ++s) {
    sv += gslice[base + s * BIN_SZ];
    mk |= (int)gmask[base + s * BIN_SZ];
  }
  int d = bin * BIN_SZ + tid;
  if (d < NDST && mk) {
    int node = ASS0 + d;
    float nv = mem[node] + sv;
    u2v lt = ltv[node];  // only this block ever writes this node's ltv
    if (lt.x == 255u) {  // first receipt: becomes working, fires next round
      u2v nl;
      nl.x = (unsigned)(r + 1);
      if (node < OUT0) {
        nl.y = __float_as_uint(tanhf(nv));  // snapshot at fire time
        ltv[node] = nl;
        mem[node] = 0.f;  // fired neurons erase memory
        newfront = 1;     // benign LDS race
      } else {
        nl.y = 0u;
        ltv[node] = nl;
        mem[node] = nv;  // outputs never fire, just accumulate
      }
    } else {
      mem[node] = nv;
    }
  }
  __syncthreads();
  if (tid == 0 && newfront) flags[r + 1] = 1;
}

// rounds 2..23 in ONE cooperative kernel over the survivors list (or full
// csr if the survivor buffer overflowed). Exits the moment a round is empty.
__global__ __launch_bounds__(1024) void kTail(int* flags,
                                              const int* __restrict__ bin_cursor,
                                              const u2v* __restrict__ csr,
                                              const u2v* __restrict__ ssur,
                                              const int* __restrict__ scur,
                                              float* __restrict__ mem,
                                              u2v* __restrict__ ltv, int cap,
                                              int scap) {
  cg::grid_group g = cg::this_grid();
  __shared__ float slice[BIN_SZ];
  __shared__ int smask[BIN_SZ];
  __shared__ int newfront;
  int tid = threadIdx.x;
  int bin = blockIdx.x;
  bool useS = (flags[30] == 0);
  int e0 = useS ? bin * scap : bin * cap;
  int e1 = useS ? min(scur[bin], bin * scap + scap) : bin_cursor[bin];
  const u2v* E = useS ? ssur : csr;
  for (int r = 2; r < NUM_ROUNDS; ++r) {
    if (flags[r] == 0) return;  // uniform across grid
    if (tid < BIN_SZ) {
      slice[tid] = 0.f;
      smask[tid] = 0;
    }
    if (tid == 0) newfront = 0;
    __syncthreads();
    unsigned rl = (unsigned)r;
    for (int e = e0 + tid; e < e1; e += 1024) {
      u2v q = E[e];
      u2v lt = ltv[q.x >> BIN_SH];
      if (lt.x == rl) {
        atomicAdd(&slice[q.x & BIN_MK],
                  __uint_as_float(lt.y) * __uint_as_float(q.y));
        smask[q.x & BIN_MK] = 1;
      }
    }
    __syncthreads();
    if (tid < BIN_SZ) {
      int d = bin * BIN_SZ + tid;
      if (d < NDST && smask[tid]) {
        int node = ASS0 + d;
        float nv = mem[node] + slice[tid];
        u2v lt = ltv[node];
        if (lt.x == 255u) {
          u2v nl;
          nl.x = (unsigned)(r + 1);
          if (node < OUT0) {
            nl.y = __float_as_uint(tanhf(nv));
            ltv[node] = nl;
            mem[node] = 0.f;
            newfront = 1;
          } else {
            nl.y = 0u;
            ltv[node] = nl;
            mem[node] = nv;
          }
        } else {
          mem[node] = nv;
        }
      }
    }
    __syncthreads();
    if (tid == 0 && newfront) flags[r + 1] = 1;
    g.sync();
  }
}

__global__ __launch_bounds__(256) void ko(const float* __restrict__ mem,
                                          float* __restrict__ out) {
  int i = blockIdx.x * 256 + threadIdx.x;
  if (i < OUT_F) out[i] = tanhf(mem[OUT0 + i]);
}

// ---------------------------------------------------------------------------
// Fallback dense multi-kernel path if ws too small.
// ---------------------------------------------------------------------------

__global__ __launch_bounds__(256) void k_init(float* mem, float* delta,
                                              int* status, int* got) {
  int i = blockIdx.x * 256 + threadIdx.x;
  if (i < TOTAL) {
    mem[i] = 0.f;
    delta[i] = 0.f;
    status[i] = 0;
    got[i] = 0;
  }
}
__global__ __launch_bounds__(256) void k_input(const float* __restrict__ x,
                                               const float* __restrict__ w,
                                               const int* __restrict__ src,
                                               const int* __restrict__ dst,
                                               int n, float* mem, int* got) {
  for (int e = blockIdx.x * 256 + threadIdx.x; e < n; e += gridDim.x * 256) {
    atomicAdd(&mem[dst[e]], x[src[e]] * w[e]);
    got[dst[e]] = 1;
  }
}
__global__ __launch_bounds__(256) void k_status0(int* status, int* got) {
  int i = blockIdx.x * 256 + threadIdx.x;
  if (i < TOTAL) {
    status[i] = got[i] ? 1 : 0;
    got[i] = 0;
  }
}
__global__ __launch_bounds__(256) void k_edge(const float* __restrict__ w,
                                              const int* __restrict__ src,
                                              const int* __restrict__ dst,
                                              int n,
                                              const float* __restrict__ mem,
                                              const int* __restrict__ status,
                                              float* delta, int* got) {
  for (int e = blockIdx.x * 256 + threadIdx.x; e < n; e += gridDim.x * 256) {
    int s = src[e];
    if (status[s] == 1) {
      atomicAdd(&delta[dst[e]], tanhf(mem[s]) * w[e]);
      got[dst[e]] = 1;
    }
  }
}
__global__ __launch_bounds__(256) void k_update(float* mem, float* delta,
                                                int* status, int* got) {
  int i = blockIdx.x * 256 + threadIdx.x;
  if (i < TOTAL) {
    int st = status[i];
    bool fire = (st == 1) && (i >= ASS0) && (i < OUT0);
    float d = delta[i];
    mem[i] = fire ? d : (mem[i] + d);
    status[i] = fire ? 2 : ((got[i] && st == 0) ? 1 : st);
    delta[i] = 0.f;
    got[i] = 0;
  }
}

extern "C" void kernel_launch(void* const* d_in, const int* in_sizes, int n_in,
                              void* d_out, int out_size, void* d_ws,
                              size_t ws_size, hipStream_t stream) {
  const float* x = (const float*)d_in[0];
  const float* iw = (const float*)d_in[1];
  const float* aw = (const float*)d_in[2];
  const int* ies = (const int*)d_in[3];
  const int* ied = (const int*)d_in[4];
  const int* aes = (const int*)d_in[5];
  const int* aed = (const int*)d_in[6];
  int E_in = in_sizes[1];
  int E_a = in_sizes[2];
  float* out = (float*)d_out;
  char* ws = (char*)d_ws;

  // fixed per-bin capacity: 1.3x mean, rounded to 256 (≈48 sigma margin)
  int cap = (((E_a / NBINS) * 13) / 10 + 255) & ~255;
  int scap = cap / 4;

  // layout: csr | ssur | ltv | mem | bin_cursor | scur | flags | gslice |
  //         gmask
  size_t off_csr = 0;
  size_t off_ssur = off_csr + (size_t)NBINS * cap * 8;
  size_t off_ltv = off_ssur + (size_t)NBINS * scap * 8;
  size_t off_mem = off_ltv + (size_t)TOTAL * 8;
  size_t off_bcur = off_mem + (size_t)TOTAL * 4;
  size_t off_scur = off_bcur + (size_t)NBINS * 4;
  size_t off_flags = off_scur + (size_t)NBINS * 4;
  size_t off_gsl = off_flags + 32 * 4;
  size_t off_gmk = off_gsl + (size_t)NBINS * SPLIT * BIN_SZ * 4;
  size_t need = off_gmk + (size_t)NBINS * SPLIT * BIN_SZ;

  if (ws_size >= need) {
    u2v* csr = (u2v*)(ws + off_csr);
    u2v* ssur = (u2v*)(ws + off_ssur);
    u2v* ltv = (u2v*)(ws + off_ltv);
    float* mem = (float*)(ws + off_mem);
    int* bin_cursor = (int*)(ws + off_bcur);
    int* scur = (int*)(ws + off_scur);
    int* flags = (int*)(ws + off_flags);
    float* gslice = (float*)(ws + off_gsl);
    char* gmask = ws + off_gmk;

    kz<<<(TOTAL + 255) / 256, 256, 0, stream>>>(mem, ltv, flags, bin_cursor,
                                                scur, cap, scap);
    ki<<<(E_in + 255) / 256, 256, 0, stream>>>(x, iw, ies, ied, E_in, mem,
                                               (unsigned int*)ltv);
    kp<<<(ASS + 255) / 256, 256, 0, stream>>>(mem, ltv);
    kc<<<NCON, CON_T, 0, stream>>>(aes, aed, aw, E_a, bin_cursor, csr);

    for (int r = 0; r < 2; ++r) {
      kRe<<<NBINS * SPLIT, 256, 0, stream>>>(r, r == 1 ? 1 : 0, flags,
                                             bin_cursor, csr, ltv, gslice,
                                             gmask, ssur, scur, cap, scap);
      kRn<<<NBINS, 512, 0, stream>>>(r, flags, gslice, gmask, mem, ltv);
    }
    void* targs[] = {(void*)&flags, (void*)&bin_cursor, (void*)&csr,
                     (void*)&ssur,  (void*)&scur,       (void*)&mem,
                     (void*)&ltv,   (void*)&cap,        (void*)&scap};
    hipLaunchCooperativeKernel((void*)kTail, dim3(NBINS), dim3(1024), targs, 0,
                               stream);

    ko<<<(OUT_F + 255) / 256, 256, 0, stream>>>(mem, out);
    return;
  }

  // fallback: dense path
  float* mem = (float*)ws;
  float* delta = mem + TOTAL;
  int* status = (int*)(delta + TOTAL);
  int* got = status + TOTAL;
  const int nodeBlocks = (TOTAL + 255) / 256;
  k_init<<<nodeBlocks, 256, 0, stream>>>(mem, delta, status, got);
  int inBlocks = (E_in + 255) / 256;
  if (inBlocks > 1024) inBlocks = 1024;
  k_input<<<inBlocks, 256, 0, stream>>>(x, iw, ies, ied, E_in, mem, got);
  k_status0<<<nodeBlocks, 256, 0, stream>>>(status, got);
  int eBlocks = (E_a + 255) / 256;
  if (eBlocks > 2048) eBlocks = 2048;
  for (int r = 0; r < NUM_ROUNDS; ++r) {
    k_edge<<<eBlocks, 256, 0, stream>>>(aw, aes, aed, E_a, mem, status, delta,
                                        got);
    k_update<<<nodeBlocks, 256, 0, stream>>>(mem, delta, status, got);
  }
  ko<<<(OUT_F + 255) / 256, 256, 0, stream>>>(mem, out);
}